// Round 13
// baseline (479.144 us; speedup 1.0000x reference)
//
#include <hip/hip_runtime.h>

#define NN 50000
#define DD 128
#define EE 100000
#define ET (EE + NN)

typedef __attribute__((ext_vector_type(4))) float f32x4;
typedef __attribute__((ext_vector_type(8))) short bf16x8;
typedef __attribute__((ext_vector_type(4))) unsigned short u16x4;
typedef __attribute__((ext_vector_type(4))) unsigned int u32x4;
typedef __attribute__((ext_vector_type(2))) unsigned int u32x2;

static __device__ __forceinline__ unsigned short f2bf(float f) {
  union { float f; unsigned int u; } v; v.f = f;
  unsigned int r = (v.u + 0x7FFFu + ((v.u >> 16) & 1u)) >> 16;
  return (unsigned short)r;
}
static __device__ __forceinline__ float bflo(unsigned int u) {
  union { unsigned int u; float f; } v; v.u = u << 16; return v.f;
}
static __device__ __forceinline__ float bfhi(unsigned int u) {
  union { unsigned int u; float f; } v; v.u = u & 0xffff0000u; return v.f;
}

// VALU-only cross-lane add via DPP (no LDS pipe, no lgkmcnt):
template <int CTRL>
static __device__ __forceinline__ float dpp_add(float x) {
  int xi = __builtin_bit_cast(int, x);
  int yi = __builtin_amdgcn_update_dpp(xi, xi, CTRL, 0xF, 0xF, true);
  return x + __builtin_bit_cast(float, yi);
}
static __device__ __forceinline__ float row16_sum(float p) {
  p = dpp_add<0xB1>(p);    // quad_perm [1,0,3,2]  (xor 1)
  p = dpp_add<0x4E>(p);    // quad_perm [2,3,0,1]  (xor 2)
  p = dpp_add<0x141>(p);   // row_half_mirror      (pairs quads 0<->1)
  p = dpp_add<0x128>(p);   // row_ror:8            (pairs 8-halves)
  return p;
}

// ---------------- W transpose via LDS tiles + zero counts ----------------
__global__ __launch_bounds__(256) void k_wtr(
    const float* __restrict__ W1l, const float* __restrict__ W1r,
    const float* __restrict__ W2l, const float* __restrict__ W2r,
    const float* __restrict__ W3l, const float* __restrict__ W3r,
    unsigned short* __restrict__ wt1, unsigned short* __restrict__ wt2,
    unsigned short* __restrict__ wt3, int* __restrict__ counts) {
  // zero counts (grid-stride; k_prep's atomics run in a later kernel)
  for (int i = blockIdx.x * 256 + threadIdx.x; i < NN; i += 160 * 256) counts[i] = 0;

  __shared__ float t[64][65];
  int b = blockIdx.x;
  const float* W; unsigned short* WT; int Nout, lgn;
  int half, tile;
  if (b < 64) {
    half = b >> 5; tile = b & 31; W = half ? W1r : W1l;
    WT = wt1 + (size_t)half * 131072; Nout = 1024; lgn = 4;
  } else if (b < 128) {
    b -= 64; half = b >> 5; tile = b & 31; W = half ? W2r : W2l;
    WT = wt2 + (size_t)half * 131072; Nout = 1024; lgn = 4;
  } else {
    b -= 128; half = b >> 4; tile = b & 15; W = half ? W3r : W3l;
    WT = wt3 + (size_t)half * 65536; Nout = 512; lgn = 3;
  }
  const int k0 = (tile >> lgn) << 6;
  const int n0 = (tile & ((1 << lgn) - 1)) << 6;
  const int wv = threadIdx.x >> 6, ln = threadIdx.x & 63;
#pragma unroll
  for (int r = 0; r < 16; ++r) {
    int row = r * 4 + wv;
    t[row][ln] = W[(size_t)(k0 + row) * Nout + n0 + ln];   // coalesced 256B
  }
  __syncthreads();
#pragma unroll
  for (int r = 0; r < 16; ++r) {
    int nrow = r * 4 + wv;
    WT[(size_t)(n0 + nrow) * 128 + k0 + ln] = f2bf(t[ln][nrow]);  // coalesced 128B
  }
}

// ---------------- fused prep: att*log2e, edge count, x->bf16 ----------------
__global__ __launch_bounds__(256) void k_prep(
    const float* __restrict__ x, const int* __restrict__ ei,
    const float* __restrict__ att1, const float* __restrict__ att2, const float* __restrict__ att3,
    float* __restrict__ as1, float* __restrict__ as2, float* __restrict__ as3,
    unsigned short* __restrict__ abf, int* __restrict__ counts) {
  const int i = blockIdx.x * 256 + threadIdx.x;
  const float LOG2E = 1.4426950408889634f;
  if (i < 2560) {                        // att scales
    if (i < 1024) as1[i] = att1[i] * LOG2E;
    else if (i < 2048) as2[i - 1024] = att2[i - 1024] * LOG2E;
    else as3[i - 2048] = att3[i - 2048] * LOG2E;
  } else if (i < 152560) {               // edge count (incl. self loops)
    int e = i - 2560;
    int dst = (e < EE) ? ei[EE + e] : (e - EE);
    if (dst >= 0 && dst < NN) atomicAdd(&counts[dst], 1);
  } else if (i < 1752560) {              // x -> bf16 (4 elems/thread)
    int u = i - 152560;
    f32x4 v = *(const f32x4*)(x + (size_t)u * 4);
    u16x4 w;
    w.x = f2bf(v.x); w.y = f2bf(v.y); w.z = f2bf(v.z); w.w = f2bf(v.w);
    *(u16x4*)(abf + (size_t)u * 4) = w;
  }
}

__global__ __launch_bounds__(1024) void k_scan(const int* __restrict__ counts,
                                               int* __restrict__ offs,
                                               int* __restrict__ cursor) {
  __shared__ int wsum[16];
  __shared__ int wpre[16];
  __shared__ int wtot;
  const int tid = threadIdx.x;
  const int wv = tid >> 6, lane = tid & 63;
  int carry = 0;
  for (int base = 0; base < NN; base += 4096) {
    int i0 = base + tid * 4;
    int v[4];
#pragma unroll
    for (int q = 0; q < 4; ++q) { int i = i0 + q; v[q] = (i < NN) ? counts[i] : 0; }
    int s = v[0] + v[1] + v[2] + v[3];
    int sc = s;  // inclusive wave scan
#pragma unroll
    for (int m = 1; m < 64; m <<= 1) {
      int t = __shfl_up(sc, m, 64);
      if (lane >= m) sc += t;
    }
    if (lane == 63) wsum[wv] = sc;
    __syncthreads();
    if (tid < 16) {
      int t = wsum[tid];
      int scc = t;
#pragma unroll
      for (int m = 1; m < 16; m <<= 1) {
        int u = __shfl_up(scc, m, 64);
        if (tid >= m) scc += u;
      }
      wpre[tid] = scc - t;
      if (tid == 15) wtot = scc;
    }
    __syncthreads();
    int excl = carry + wpre[wv] + (sc - s);
#pragma unroll
    for (int q = 0; q < 4; ++q) {
      int i = i0 + q;
      if (i < NN) { offs[i] = excl; cursor[i] = excl; }
      excl += v[q];
    }
    carry += wtot;
    __syncthreads();
  }
  if (tid == 0) offs[NN] = carry;
}

__global__ void k_fill(const int* __restrict__ ei, int* __restrict__ cursor,
                       int* __restrict__ srcs) {
  int i = blockIdx.x * blockDim.x + threadIdx.x;
  if (i >= ET) return;
  int src, dst;
  if (i < EE) { src = ei[i]; dst = ei[EE + i]; }
  else { src = dst = i - EE; }
  if (dst < 0 || dst >= NN) return;
  if (src < 0 || src >= NN) src = dst;
  int pos = atomicAdd(&cursor[dst], 1);
  if (pos >= 0 && pos < ET) srcs[pos] = src;
}

// ---------------- GEMM 64x64 (round-11 epilogue: direct stores) ----------------
__global__ __launch_bounds__(256) void gemm64(
    const unsigned short* __restrict__ A, const unsigned short* __restrict__ WT,
    unsigned short* __restrict__ Cl, unsigned short* __restrict__ Cr,
    int M, int Nout, int lgnc) {
  const int f = (blockIdx.x & 7) * (gridDim.x >> 3) + (blockIdx.x >> 3);
  const int c = f & ((1 << lgnc) - 1);
  const int x = f >> lgnc;
  const int z = c & 1, y = c >> 1;
  const int m0 = x * 64, n0 = y * 64;
  unsigned short* C = z ? Cr : Cl;
  const unsigned short* BT = WT + (size_t)z * Nout * DD;

  __shared__ unsigned short As[64 * 128];
  __shared__ unsigned short Bs[64 * 128];
  const int tid = threadIdx.x;
  const int wave = tid >> 6, lane = tid & 63;
  const int hi = lane >> 4, lr = lane & 15;

#pragma unroll
  for (int i = 0; i < 4; ++i) {
    int row = i * 16 + wave * 4 + hi;
    int c16 = lr ^ (row & 7);
    const unsigned short* ga = A + (size_t)(m0 + row) * DD + c16 * 8;
    __builtin_amdgcn_global_load_lds((const __attribute__((address_space(1))) void*)ga,
        (__attribute__((address_space(3))) void*)(As + i * 2048 + wave * 512), 16, 0, 0);
    const unsigned short* gb = BT + (size_t)(n0 + row) * DD + c16 * 8;
    __builtin_amdgcn_global_load_lds((const __attribute__((address_space(1))) void*)gb,
        (__attribute__((address_space(3))) void*)(Bs + i * 2048 + wave * 512), 16, 0, 0);
  }
  __syncthreads();

  const int wr = (wave >> 1) * 32, wc = (wave & 1) * 32;
  f32x4 acc[2][2];
#pragma unroll
  for (int i = 0; i < 2; ++i)
#pragma unroll
    for (int j = 0; j < 2; ++j) acc[i][j] = (f32x4){0.f, 0.f, 0.f, 0.f};

#pragma unroll
  for (int k0 = 0; k0 < 128; k0 += 32) {
    const int ck = (k0 >> 3) + hi;
    bf16x8 af[2], bfr[2];
#pragma unroll
    for (int mi = 0; mi < 2; ++mi) {
      int r = wr + mi * 16 + lr;
      af[mi] = *(const bf16x8*)&As[r * 128 + ((ck ^ (r & 7)) << 3)];
    }
#pragma unroll
    for (int ni = 0; ni < 2; ++ni) {
      int cc = wc + ni * 16 + lr;
      bfr[ni] = *(const bf16x8*)&Bs[cc * 128 + ((ck ^ (cc & 7)) << 3)];
    }
#pragma unroll
    for (int mi = 0; mi < 2; ++mi)
#pragma unroll
      for (int ni = 0; ni < 2; ++ni)
        acc[mi][ni] = __builtin_amdgcn_mfma_f32_16x16x32_bf16(af[mi], bfr[ni], acc[mi][ni], 0, 0, 0);
  }

#pragma unroll
  for (int mi = 0; mi < 2; ++mi) {
#pragma unroll
    for (int ni = 0; ni < 2; ++ni) {
      int col = n0 + wc + ni * 16 + lr;
#pragma unroll
      for (int j = 0; j < 4; ++j) {
        int row = m0 + wr + mi * 16 + (hi << 2) + j;
        if (row < M) C[(size_t)row * Nout + col] = f2bf(acc[mi][ni][j]);
      }
    }
  }
}

// ---------------- fused score + softmax + aggregation (r11 + resid prefetch) ----------
template <int H>
__global__ __launch_bounds__(256) void gat_agg9(
    const unsigned short* __restrict__ xl, const unsigned short* __restrict__ xr,
    const int* __restrict__ offs, const int* __restrict__ srcs,
    const float* __restrict__ att_s,  // att * log2(e), [H][128]
    const float* __restrict__ bias,
    const float* __restrict__ residf,           // f32 residual (layer 1) or null
    const unsigned short* __restrict__ residb,  // bf16 residual (layers 2,3) or null
    float* __restrict__ outf,                   // f32 output (layer 3) or null
    unsigned short* __restrict__ hbfw,          // bf16 h output (layers 1,2) or null
    int do_elu) {
  constexpr int HG = H / 2;         // heads per wave
  constexpr int CPL = 2 * HG;       // channels per lane (= H)
  constexpr int NW = HG;            // u32 words per lane
  constexpr int LPH = 128 / CPL;    // lanes per head (16 for H=8, 32 for H=4)
  constexpr int ROW = H * DD;       // halfwords per full row
  constexpr int HALFROW = ROW / 2;
  const int wave = threadIdx.x >> 6, lane = threadIdx.x & 63;
  const int nsub = wave >> 1, g = wave & 1;
  const int n = blockIdx.x * 2 + nsub;
  if (n >= NN) return;
  const int cb = g * HALFROW + lane * CPL;   // halfword offset within row
  const int d0 = (lane * CPL) & 127;

  // prefetch residual EARLY (independent of edge loop; hides a serial round-trip)
  float rv[CPL];
  const bool writer = (g == 0) && (lane < LPH);
  if (writer) {
    if (residf) {
#pragma unroll
      for (int c = 0; c < CPL; c += 4) {
        f32x4 v = *(const f32x4*)(residf + (size_t)n * DD + d0 + c);
        rv[c] = v.x; rv[c + 1] = v.y; rv[c + 2] = v.z; rv[c + 3] = v.w;
      }
    } else {
      unsigned int uw[CPL / 2];
      if constexpr (CPL == 8) {
        u32x4 v = *(const u32x4*)(residb + (size_t)n * DD + d0);
        uw[0] = v.x; uw[1] = v.y; uw[2] = v.z; uw[3] = v.w;
      } else {
        u32x2 v = *(const u32x2*)(residb + (size_t)n * DD + d0);
        uw[0] = v.x; uw[1] = v.y;
      }
#pragma unroll
      for (int w = 0; w < CPL / 2; ++w) {
        rv[2 * w] = bflo(uw[w]);
        rv[2 * w + 1] = bfhi(uw[w]);
      }
    }
  }

  float xrv[CPL], av[CPL];
  {
    unsigned int uw[NW];
    if constexpr (NW == 4) {
      u32x4 v = *(const u32x4*)(xr + (size_t)n * ROW + cb);
      uw[0] = v.x; uw[1] = v.y; uw[2] = v.z; uw[3] = v.w;
    } else {
      u32x2 v = *(const u32x2*)(xr + (size_t)n * ROW + cb);
      uw[0] = v.x; uw[1] = v.y;
    }
#pragma unroll
    for (int w = 0; w < NW; ++w) {
      xrv[2 * w] = bflo(uw[w]);
      xrv[2 * w + 1] = bfhi(uw[w]);
    }
#pragma unroll
    for (int c = 0; c < CPL; ++c) av[c] = att_s[cb + c];
  }

  float acc[CPL];
#pragma unroll
  for (int c = 0; c < CPL; ++c) acc[c] = 0.f;
  float mx = -1e30f, dn = 0.f;

  const int e0 = offs[n], e1 = offs[n + 1];
  const unsigned short* xl_cb = xl + cb;
  for (int j = e0; j < e1; j += 4) {
    const int B = (e1 - j < 4) ? (e1 - j) : 4;
    unsigned int rows[4][NW];
#pragma unroll
    for (int b = 0; b < 4; ++b) {
      if (b < B) {
        int s = srcs[j + b];
        if constexpr (NW == 4) {
          u32x4 v = *(const u32x4*)(xl_cb + (size_t)s * ROW);
          rows[b][0] = v.x; rows[b][1] = v.y; rows[b][2] = v.z; rows[b][3] = v.w;
        } else {
          u32x2 v = *(const u32x2*)(xl_cb + (size_t)s * ROW);
          rows[b][0] = v.x; rows[b][1] = v.y;
        }
      }
    }
    float p[4];
#pragma unroll
    for (int b = 0; b < 4; ++b) {
      float pp = -1e30f;
      if (b < B) {
        pp = 0.f;
#pragma unroll
        for (int w = 0; w < NW; ++w) {
          float x0 = bflo(rows[b][w]), x1 = bfhi(rows[b][w]);
          float z0 = x0 + xrv[2 * w]; z0 = fmaxf(z0, 0.2f * z0);
          float z1 = x1 + xrv[2 * w + 1]; z1 = fmaxf(z1, 0.2f * z1);
          pp = fmaf(z0, av[2 * w], pp);
          pp = fmaf(z1, av[2 * w + 1], pp);
        }
        pp = row16_sum(pp);                       // VALU DPP butterfly
        if constexpr (LPH == 32) pp += __shfl_xor(pp, 16, 64);
      }
      p[b] = pp;
    }
    float pm = fmaxf(fmaxf(p[0], p[1]), fmaxf(p[2], p[3]));
    if (__any(pm > mx + 11.5f)) {        // defer-max rescale (log2 units)
      float mnew = fmaxf(mx, pm);
      float sc = __builtin_amdgcn_exp2f(mx - mnew);
      dn *= sc;
#pragma unroll
      for (int c = 0; c < CPL; ++c) acc[c] *= sc;
      mx = mnew;
    }
#pragma unroll
    for (int b = 0; b < 4; ++b) {
      if (b < B) {
        float wt = __builtin_amdgcn_exp2f(p[b] - mx);
        dn += wt;
#pragma unroll
        for (int w = 0; w < NW; ++w) {
          acc[2 * w] = fmaf(wt, bflo(rows[b][w]), acc[2 * w]);
          acc[2 * w + 1] = fmaf(wt, bfhi(rows[b][w]), acc[2 * w + 1]);
        }
      }
    }
  }

  // normalize per head, butterfly-sum this wave's HG heads
  float r[CPL];
  const float inv = (1.f / (float)H) / dn;
#pragma unroll
  for (int c = 0; c < CPL; ++c) r[c] = acc[c] * inv;
#pragma unroll
  for (int m = LPH; m < 64; m <<= 1)
#pragma unroll
    for (int c = 0; c < CPL; ++c) r[c] += __shfl_xor(r[c], m, 64);

  __shared__ float lds[2][DD];
  if (g == 1 && lane < LPH) {
#pragma unroll
    for (int c = 0; c < CPL; ++c) lds[nsub][d0 + c] = r[c];
  }
  __syncthreads();
  if (writer) {
    float o[CPL];
#pragma unroll
    for (int c = 0; c < CPL; ++c) {
      o[c] = r[c] + lds[nsub][d0 + c] + bias[d0 + c] + rv[c];
      if (do_elu && o[c] < 0.f)
        o[c] = __builtin_amdgcn_exp2f(o[c] * 1.4426950408889634f) - 1.f;
    }
    if (outf) {
#pragma unroll
      for (int c = 0; c < CPL; c += 4) {
        f32x4 v; v.x = o[c]; v.y = o[c + 1]; v.z = o[c + 2]; v.w = o[c + 3];
        *(f32x4*)(outf + (size_t)n * DD + d0 + c) = v;
      }
    }
    if (hbfw) {
      unsigned int pk[CPL / 2];
#pragma unroll
      for (int q = 0; q < CPL / 2; ++q)
        pk[q] = (unsigned int)f2bf(o[2 * q]) | ((unsigned int)f2bf(o[2 * q + 1]) << 16);
      if constexpr (CPL == 8) {
        u32x4 v; v.x = pk[0]; v.y = pk[1]; v.z = pk[2]; v.w = pk[3];
        *(u32x4*)(hbfw + (size_t)n * DD + d0) = v;
      } else {
        u32x2 v; v.x = pk[0]; v.y = pk[1];
        *(u32x2*)(hbfw + (size_t)n * DD + d0) = v;
      }
    }
  }
}

extern "C" void kernel_launch(void* const* d_in, const int* in_sizes, int n_in,
                              void* d_out, int out_size, void* d_ws, size_t ws_size,
                              hipStream_t stream) {
  const float* x = (const float*)d_in[0];
  const int* ei = (const int*)d_in[1];
  const float* W1l = (const float*)d_in[2];
  const float* W1r = (const float*)d_in[3];
  const float* att1 = (const float*)d_in[4];
  const float* b1 = (const float*)d_in[5];
  const float* W2l = (const float*)d_in[6];
  const float* W2r = (const float*)d_in[7];
  const float* att2 = (const float*)d_in[8];
  const float* b2 = (const float*)d_in[9];
  const float* W3l = (const float*)d_in[10];
  const float* W3r = (const float*)d_in[11];
  const float* att3 = (const float*)d_in[12];
  const float* b3 = (const float*)d_in[13];
  float* out = (float*)d_out;

  char* p = (char*)d_ws;
  auto carve = [&](size_t bytes) {
    char* r = p;
    p += (bytes + 255) & ~(size_t)255;
    return r;
  };
  unsigned short* xl = (unsigned short*)carve((size_t)NN * 1024 * 2);
  unsigned short* xr = (unsigned short*)carve((size_t)NN * 1024 * 2);
  unsigned short* abf = (unsigned short*)carve((size_t)NN * DD * 2);
  unsigned short* wt1 = (unsigned short*)carve((size_t)2 * 1024 * DD * 2);
  unsigned short* wt2 = (unsigned short*)carve((size_t)2 * 1024 * DD * 2);
  unsigned short* wt3 = (unsigned short*)carve((size_t)2 * 512 * DD * 2);
  float* as1 = (float*)carve((size_t)8 * DD * 4);
  float* as2 = (float*)carve((size_t)8 * DD * 4);
  float* as3 = (float*)carve((size_t)4 * DD * 4);
  int* counts = (int*)carve((size_t)NN * 4);
  int* offs = (int*)carve(((size_t)NN + 1) * 4);
  int* cursor = (int*)carve((size_t)NN * 4);
  int* srcs = (int*)carve((size_t)ET * 4);
  size_t needed = (size_t)(p - (char*)d_ws);
  if (needed > ws_size) return;

  k_wtr<<<160, 256, 0, stream>>>(W1l, W1r, W2l, W2r, W3l, W3r, wt1, wt2, wt3, counts);
  k_prep<<<6847, 256, 0, stream>>>(x, ei, att1, att2, att3, as1, as2, as3, abf, counts);
  k_scan<<<1, 1024, 0, stream>>>(counts, offs, cursor);
  k_fill<<<(ET + 255) / 256, 256, 0, stream>>>(ei, cursor, srcs);

  const int gx = (NN + 63) / 64;     // 782
  const int ga = (NN + 1) / 2;       // 25000 blocks (2 nodes each)
  // layer 1: resid = x (f32), write h -> abf (bf16 only)
  gemm64<<<gx * 32, 256, 0, stream>>>(abf, wt1, xl, xr, NN, 1024, 5);
  gat_agg9<8><<<ga, 256, 0, stream>>>(xl, xr, offs, srcs, as1, b1, x, nullptr,
                                      nullptr, abf, 1);
  // layer 2: resid = abf (bf16), write h -> abf in place
  gemm64<<<gx * 32, 256, 0, stream>>>(abf, wt2, xl, xr, NN, 1024, 5);
  gat_agg9<8><<<ga, 256, 0, stream>>>(xl, xr, offs, srcs, as2, b2, nullptr, abf,
                                      nullptr, abf, 1);
  // layer 3: resid = abf (bf16), write final f32 out
  gemm64<<<gx * 16, 256, 0, stream>>>(abf, wt3, xl, xr, NN, 512, 4);
  gat_agg9<4><<<ga, 256, 0, stream>>>(xl, xr, offs, srcs, as3, b3, nullptr, abf,
                                      out, nullptr, 0);
}

// Round 14
// 444.332 us; speedup vs baseline: 1.0783x; 1.0783x over previous
//
#include <hip/hip_runtime.h>

#define NN 50000
#define DD 128
#define EE 100000
#define ET (EE + NN)

typedef __attribute__((ext_vector_type(4))) float f32x4;
typedef __attribute__((ext_vector_type(8))) short bf16x8;
typedef __attribute__((ext_vector_type(4))) unsigned short u16x4;
typedef __attribute__((ext_vector_type(4))) unsigned int u32x4;
typedef __attribute__((ext_vector_type(2))) unsigned int u32x2;

static __device__ __forceinline__ unsigned short f2bf(float f) {
  union { float f; unsigned int u; } v; v.f = f;
  unsigned int r = (v.u + 0x7FFFu + ((v.u >> 16) & 1u)) >> 16;
  return (unsigned short)r;
}
static __device__ __forceinline__ float bflo(unsigned int u) {
  union { unsigned int u; float f; } v; v.u = u << 16; return v.f;
}
static __device__ __forceinline__ float bfhi(unsigned int u) {
  union { unsigned int u; float f; } v; v.u = u & 0xffff0000u; return v.f;
}

// VALU-only cross-lane add via DPP (no LDS pipe, no lgkmcnt):
template <int CTRL>
static __device__ __forceinline__ float dpp_add(float x) {
  int xi = __builtin_bit_cast(int, x);
  int yi = __builtin_amdgcn_update_dpp(xi, xi, CTRL, 0xF, 0xF, true);
  return x + __builtin_bit_cast(float, yi);
}
static __device__ __forceinline__ float row16_sum(float p) {
  p = dpp_add<0xB1>(p);    // quad_perm [1,0,3,2]  (xor 1)
  p = dpp_add<0x4E>(p);    // quad_perm [2,3,0,1]  (xor 2)
  p = dpp_add<0x141>(p);   // row_half_mirror      (pairs quads 0<->1)
  p = dpp_add<0x128>(p);   // row_ror:8            (pairs 8-halves)
  return p;
}

// ---------------- W transpose via LDS tiles + zero counts ----------------
__global__ __launch_bounds__(256) void k_wtr(
    const float* __restrict__ W1l, const float* __restrict__ W1r,
    const float* __restrict__ W2l, const float* __restrict__ W2r,
    const float* __restrict__ W3l, const float* __restrict__ W3r,
    unsigned short* __restrict__ wt1, unsigned short* __restrict__ wt2,
    unsigned short* __restrict__ wt3, int* __restrict__ counts) {
  // zero counts (grid-stride; k_prep's atomics run in a later kernel)
  for (int i = blockIdx.x * 256 + threadIdx.x; i < NN; i += 160 * 256) counts[i] = 0;

  __shared__ float t[64][65];
  int b = blockIdx.x;
  const float* W; unsigned short* WT; int Nout, lgn;
  int half, tile;
  if (b < 64) {
    half = b >> 5; tile = b & 31; W = half ? W1r : W1l;
    WT = wt1 + (size_t)half * 131072; Nout = 1024; lgn = 4;
  } else if (b < 128) {
    b -= 64; half = b >> 5; tile = b & 31; W = half ? W2r : W2l;
    WT = wt2 + (size_t)half * 131072; Nout = 1024; lgn = 4;
  } else {
    b -= 128; half = b >> 4; tile = b & 15; W = half ? W3r : W3l;
    WT = wt3 + (size_t)half * 65536; Nout = 512; lgn = 3;
  }
  const int k0 = (tile >> lgn) << 6;
  const int n0 = (tile & ((1 << lgn) - 1)) << 6;
  const int wv = threadIdx.x >> 6, ln = threadIdx.x & 63;
#pragma unroll
  for (int r = 0; r < 16; ++r) {
    int row = r * 4 + wv;
    t[row][ln] = W[(size_t)(k0 + row) * Nout + n0 + ln];   // coalesced 256B
  }
  __syncthreads();
#pragma unroll
  for (int r = 0; r < 16; ++r) {
    int nrow = r * 4 + wv;
    WT[(size_t)(n0 + nrow) * 128 + k0 + ln] = f2bf(t[ln][nrow]);  // coalesced 128B
  }
}

// ---------------- fused prep: att*log2e, edge count, x->bf16 ----------------
__global__ __launch_bounds__(256) void k_prep(
    const float* __restrict__ x, const int* __restrict__ ei,
    const float* __restrict__ att1, const float* __restrict__ att2, const float* __restrict__ att3,
    float* __restrict__ as1, float* __restrict__ as2, float* __restrict__ as3,
    unsigned short* __restrict__ abf, int* __restrict__ counts) {
  const int i = blockIdx.x * 256 + threadIdx.x;
  const float LOG2E = 1.4426950408889634f;
  if (i < 2560) {                        // att scales
    if (i < 1024) as1[i] = att1[i] * LOG2E;
    else if (i < 2048) as2[i - 1024] = att2[i - 1024] * LOG2E;
    else as3[i - 2048] = att3[i - 2048] * LOG2E;
  } else if (i < 152560) {               // edge count (incl. self loops)
    int e = i - 2560;
    int dst = (e < EE) ? ei[EE + e] : (e - EE);
    if (dst >= 0 && dst < NN) atomicAdd(&counts[dst], 1);
  } else if (i < 1752560) {              // x -> bf16 (4 elems/thread)
    int u = i - 152560;
    f32x4 v = *(const f32x4*)(x + (size_t)u * 4);
    u16x4 w;
    w.x = f2bf(v.x); w.y = f2bf(v.y); w.z = f2bf(v.z); w.w = f2bf(v.w);
    *(u16x4*)(abf + (size_t)u * 4) = w;
  }
}

__global__ __launch_bounds__(1024) void k_scan(const int* __restrict__ counts,
                                               int* __restrict__ offs,
                                               int* __restrict__ cursor) {
  __shared__ int wsum[16];
  __shared__ int wpre[16];
  __shared__ int wtot;
  const int tid = threadIdx.x;
  const int wv = tid >> 6, lane = tid & 63;
  int carry = 0;
  for (int base = 0; base < NN; base += 4096) {
    int i0 = base + tid * 4;
    int v[4];
#pragma unroll
    for (int q = 0; q < 4; ++q) { int i = i0 + q; v[q] = (i < NN) ? counts[i] : 0; }
    int s = v[0] + v[1] + v[2] + v[3];
    int sc = s;  // inclusive wave scan
#pragma unroll
    for (int m = 1; m < 64; m <<= 1) {
      int t = __shfl_up(sc, m, 64);
      if (lane >= m) sc += t;
    }
    if (lane == 63) wsum[wv] = sc;
    __syncthreads();
    if (tid < 16) {
      int t = wsum[tid];
      int scc = t;
#pragma unroll
      for (int m = 1; m < 16; m <<= 1) {
        int u = __shfl_up(scc, m, 64);
        if (tid >= m) scc += u;
      }
      wpre[tid] = scc - t;
      if (tid == 15) wtot = scc;
    }
    __syncthreads();
    int excl = carry + wpre[wv] + (sc - s);
#pragma unroll
    for (int q = 0; q < 4; ++q) {
      int i = i0 + q;
      if (i < NN) { offs[i] = excl; cursor[i] = excl; }
      excl += v[q];
    }
    carry += wtot;
    __syncthreads();
  }
  if (tid == 0) offs[NN] = carry;
}

__global__ void k_fill(const int* __restrict__ ei, int* __restrict__ cursor,
                       int* __restrict__ srcs) {
  int i = blockIdx.x * blockDim.x + threadIdx.x;
  if (i >= ET) return;
  int src, dst;
  if (i < EE) { src = ei[i]; dst = ei[EE + i]; }
  else { src = dst = i - EE; }
  if (dst < 0 || dst >= NN) return;
  if (src < 0 || src >= NN) src = dst;
  int pos = atomicAdd(&cursor[dst], 1);
  if (pos >= 0 && pos < ET) srcs[pos] = src;
}

// ---------------- GEMM 64x64 (round-11: direct-store epilogue) ----------------
__global__ __launch_bounds__(256) void gemm64(
    const unsigned short* __restrict__ A, const unsigned short* __restrict__ WT,
    unsigned short* __restrict__ Cl, unsigned short* __restrict__ Cr,
    int M, int Nout, int lgnc) {
  const int f = (blockIdx.x & 7) * (gridDim.x >> 3) + (blockIdx.x >> 3);
  const int c = f & ((1 << lgnc) - 1);
  const int x = f >> lgnc;
  const int z = c & 1, y = c >> 1;
  const int m0 = x * 64, n0 = y * 64;
  unsigned short* C = z ? Cr : Cl;
  const unsigned short* BT = WT + (size_t)z * Nout * DD;

  __shared__ unsigned short As[64 * 128];
  __shared__ unsigned short Bs[64 * 128];
  const int tid = threadIdx.x;
  const int wave = tid >> 6, lane = tid & 63;
  const int hi = lane >> 4, lr = lane & 15;

#pragma unroll
  for (int i = 0; i < 4; ++i) {
    int row = i * 16 + wave * 4 + hi;
    int c16 = lr ^ (row & 7);
    const unsigned short* ga = A + (size_t)(m0 + row) * DD + c16 * 8;
    __builtin_amdgcn_global_load_lds((const __attribute__((address_space(1))) void*)ga,
        (__attribute__((address_space(3))) void*)(As + i * 2048 + wave * 512), 16, 0, 0);
    const unsigned short* gb = BT + (size_t)(n0 + row) * DD + c16 * 8;
    __builtin_amdgcn_global_load_lds((const __attribute__((address_space(1))) void*)gb,
        (__attribute__((address_space(3))) void*)(Bs + i * 2048 + wave * 512), 16, 0, 0);
  }
  __syncthreads();

  const int wr = (wave >> 1) * 32, wc = (wave & 1) * 32;
  f32x4 acc[2][2];
#pragma unroll
  for (int i = 0; i < 2; ++i)
#pragma unroll
    for (int j = 0; j < 2; ++j) acc[i][j] = (f32x4){0.f, 0.f, 0.f, 0.f};

#pragma unroll
  for (int k0 = 0; k0 < 128; k0 += 32) {
    const int ck = (k0 >> 3) + hi;
    bf16x8 af[2], bfr[2];
#pragma unroll
    for (int mi = 0; mi < 2; ++mi) {
      int r = wr + mi * 16 + lr;
      af[mi] = *(const bf16x8*)&As[r * 128 + ((ck ^ (r & 7)) << 3)];
    }
#pragma unroll
    for (int ni = 0; ni < 2; ++ni) {
      int cc = wc + ni * 16 + lr;
      bfr[ni] = *(const bf16x8*)&Bs[cc * 128 + ((ck ^ (cc & 7)) << 3)];
    }
#pragma unroll
    for (int mi = 0; mi < 2; ++mi)
#pragma unroll
      for (int ni = 0; ni < 2; ++ni)
        acc[mi][ni] = __builtin_amdgcn_mfma_f32_16x16x32_bf16(af[mi], bfr[ni], acc[mi][ni], 0, 0, 0);
  }

#pragma unroll
  for (int mi = 0; mi < 2; ++mi) {
#pragma unroll
    for (int ni = 0; ni < 2; ++ni) {
      int col = n0 + wc + ni * 16 + lr;
#pragma unroll
      for (int j = 0; j < 4; ++j) {
        int row = m0 + wr + mi * 16 + (hi << 2) + j;
        if (row < M) C[(size_t)row * Nout + col] = f2bf(acc[mi][ni][j]);
      }
    }
  }
}

// ---------------- fused score + softmax + aggregation (round-11 structure) ----------
template <int H>
__global__ __launch_bounds__(256) void gat_agg8(
    const unsigned short* __restrict__ xl, const unsigned short* __restrict__ xr,
    const int* __restrict__ offs, const int* __restrict__ srcs,
    const float* __restrict__ att_s,  // att * log2(e), [H][128]
    const float* __restrict__ bias,
    const float* __restrict__ residf,           // f32 residual (layer 1) or null
    const unsigned short* __restrict__ residb,  // bf16 residual (layers 2,3) or null
    float* __restrict__ outf,                   // f32 output (layer 3) or null
    unsigned short* __restrict__ hbfw,          // bf16 h output (layers 1,2) or null
    int do_elu) {
  constexpr int HG = H / 2;         // heads per wave
  constexpr int CPL = 2 * HG;       // channels per lane (= H)
  constexpr int NW = HG;            // u32 words per lane
  constexpr int LPH = 128 / CPL;    // lanes per head (16 for H=8, 32 for H=4)
  constexpr int ROW = H * DD;       // halfwords per full row
  constexpr int HALFROW = ROW / 2;
  const int wave = threadIdx.x >> 6, lane = threadIdx.x & 63;
  const int nsub = wave >> 1, g = wave & 1;
  const int n = blockIdx.x * 2 + nsub;
  if (n >= NN) return;
  const int cb = g * HALFROW + lane * CPL;   // halfword offset within row
  const int d0 = (lane * CPL) & 127;

  float xrv[CPL], av[CPL];
  {
    unsigned int uw[NW];
    if constexpr (NW == 4) {
      u32x4 v = *(const u32x4*)(xr + (size_t)n * ROW + cb);
      uw[0] = v.x; uw[1] = v.y; uw[2] = v.z; uw[3] = v.w;
    } else {
      u32x2 v = *(const u32x2*)(xr + (size_t)n * ROW + cb);
      uw[0] = v.x; uw[1] = v.y;
    }
#pragma unroll
    for (int w = 0; w < NW; ++w) {
      xrv[2 * w] = bflo(uw[w]);
      xrv[2 * w + 1] = bfhi(uw[w]);
    }
#pragma unroll
    for (int c = 0; c < CPL; ++c) av[c] = att_s[cb + c];
  }

  float acc[CPL];
#pragma unroll
  for (int c = 0; c < CPL; ++c) acc[c] = 0.f;
  float mx = -1e30f, dn = 0.f;

  const int e0 = offs[n], e1 = offs[n + 1];
  const unsigned short* xl_cb = xl + cb;
  for (int j = e0; j < e1; j += 4) {
    const int B = (e1 - j < 4) ? (e1 - j) : 4;
    unsigned int rows[4][NW];
#pragma unroll
    for (int b = 0; b < 4; ++b) {
      if (b < B) {
        int s = srcs[j + b];
        if constexpr (NW == 4) {
          u32x4 v = *(const u32x4*)(xl_cb + (size_t)s * ROW);
          rows[b][0] = v.x; rows[b][1] = v.y; rows[b][2] = v.z; rows[b][3] = v.w;
        } else {
          u32x2 v = *(const u32x2*)(xl_cb + (size_t)s * ROW);
          rows[b][0] = v.x; rows[b][1] = v.y;
        }
      }
    }
    float p[4];
#pragma unroll
    for (int b = 0; b < 4; ++b) {
      float pp = -1e30f;
      if (b < B) {
        pp = 0.f;
#pragma unroll
        for (int w = 0; w < NW; ++w) {
          float x0 = bflo(rows[b][w]), x1 = bfhi(rows[b][w]);
          float z0 = x0 + xrv[2 * w]; z0 = fmaxf(z0, 0.2f * z0);
          float z1 = x1 + xrv[2 * w + 1]; z1 = fmaxf(z1, 0.2f * z1);
          pp = fmaf(z0, av[2 * w], pp);
          pp = fmaf(z1, av[2 * w + 1], pp);
        }
        pp = row16_sum(pp);                       // VALU DPP butterfly
        if constexpr (LPH == 32) pp += __shfl_xor(pp, 16, 64);
      }
      p[b] = pp;
    }
    float pm = fmaxf(fmaxf(p[0], p[1]), fmaxf(p[2], p[3]));
    if (__any(pm > mx + 11.5f)) {        // defer-max rescale (log2 units)
      float mnew = fmaxf(mx, pm);
      float sc = __builtin_amdgcn_exp2f(mx - mnew);
      dn *= sc;
#pragma unroll
      for (int c = 0; c < CPL; ++c) acc[c] *= sc;
      mx = mnew;
    }
#pragma unroll
    for (int b = 0; b < 4; ++b) {
      if (b < B) {
        float wt = __builtin_amdgcn_exp2f(p[b] - mx);
        dn += wt;
#pragma unroll
        for (int w = 0; w < NW; ++w) {
          acc[2 * w] = fmaf(wt, bflo(rows[b][w]), acc[2 * w]);
          acc[2 * w + 1] = fmaf(wt, bfhi(rows[b][w]), acc[2 * w + 1]);
        }
      }
    }
  }

  // normalize per head, butterfly-sum this wave's HG heads
  float r[CPL];
  const float inv = (1.f / (float)H) / dn;
#pragma unroll
  for (int c = 0; c < CPL; ++c) r[c] = acc[c] * inv;
#pragma unroll
  for (int m = LPH; m < 64; m <<= 1)
#pragma unroll
    for (int c = 0; c < CPL; ++c) r[c] += __shfl_xor(r[c], m, 64);

  __shared__ float lds[2][DD];
  if (g == 1 && lane < LPH) {
#pragma unroll
    for (int c = 0; c < CPL; ++c) lds[nsub][d0 + c] = r[c];
  }
  __syncthreads();
  if (g == 0 && lane < LPH) {
    // residual (f32 for layer 1, bf16 stream after)
    float rv[CPL];
    if (residf) {
#pragma unroll
      for (int c = 0; c < CPL; c += 4) {
        f32x4 v = *(const f32x4*)(residf + (size_t)n * DD + d0 + c);
        rv[c] = v.x; rv[c + 1] = v.y; rv[c + 2] = v.z; rv[c + 3] = v.w;
      }
    } else {
      unsigned int uw[CPL / 2];
      if constexpr (CPL == 8) {
        u32x4 v = *(const u32x4*)(residb + (size_t)n * DD + d0);
        uw[0] = v.x; uw[1] = v.y; uw[2] = v.z; uw[3] = v.w;
      } else {
        u32x2 v = *(const u32x2*)(residb + (size_t)n * DD + d0);
        uw[0] = v.x; uw[1] = v.y;
      }
#pragma unroll
      for (int w = 0; w < CPL / 2; ++w) {
        rv[2 * w] = bflo(uw[w]);
        rv[2 * w + 1] = bfhi(uw[w]);
      }
    }
    float o[CPL];
#pragma unroll
    for (int c = 0; c < CPL; ++c) {
      o[c] = r[c] + lds[nsub][d0 + c] + bias[d0 + c] + rv[c];
      if (do_elu && o[c] < 0.f)
        o[c] = __builtin_amdgcn_exp2f(o[c] * 1.4426950408889634f) - 1.f;
    }
    if (outf) {
#pragma unroll
      for (int c = 0; c < CPL; c += 4) {
        f32x4 v; v.x = o[c]; v.y = o[c + 1]; v.z = o[c + 2]; v.w = o[c + 3];
        *(f32x4*)(outf + (size_t)n * DD + d0 + c) = v;
      }
    }
    if (hbfw) {
      unsigned int pk[CPL / 2];
#pragma unroll
      for (int q = 0; q < CPL / 2; ++q)
        pk[q] = (unsigned int)f2bf(o[2 * q]) | ((unsigned int)f2bf(o[2 * q + 1]) << 16);
      if constexpr (CPL == 8) {
        u32x4 v; v.x = pk[0]; v.y = pk[1]; v.z = pk[2]; v.w = pk[3];
        *(u32x4*)(hbfw + (size_t)n * DD + d0) = v;
      } else {
        u32x2 v; v.x = pk[0]; v.y = pk[1];
        *(u32x2*)(hbfw + (size_t)n * DD + d0) = v;
      }
    }
  }
}

extern "C" void kernel_launch(void* const* d_in, const int* in_sizes, int n_in,
                              void* d_out, int out_size, void* d_ws, size_t ws_size,
                              hipStream_t stream) {
  const float* x = (const float*)d_in[0];
  const int* ei = (const int*)d_in[1];
  const float* W1l = (const float*)d_in[2];
  const float* W1r = (const float*)d_in[3];
  const float* att1 = (const float*)d_in[4];
  const float* b1 = (const float*)d_in[5];
  const float* W2l = (const float*)d_in[6];
  const float* W2r = (const float*)d_in[7];
  const float* att2 = (const float*)d_in[8];
  const float* b2 = (const float*)d_in[9];
  const float* W3l = (const float*)d_in[10];
  const float* W3r = (const float*)d_in[11];
  const float* att3 = (const float*)d_in[12];
  const float* b3 = (const float*)d_in[13];
  float* out = (float*)d_out;

  char* p = (char*)d_ws;
  auto carve = [&](size_t bytes) {
    char* r = p;
    p += (bytes + 255) & ~(size_t)255;
    return r;
  };
  unsigned short* xl = (unsigned short*)carve((size_t)NN * 1024 * 2);
  unsigned short* xr = (unsigned short*)carve((size_t)NN * 1024 * 2);
  unsigned short* abf = (unsigned short*)carve((size_t)NN * DD * 2);
  unsigned short* wt1 = (unsigned short*)carve((size_t)2 * 1024 * DD * 2);
  unsigned short* wt2 = (unsigned short*)carve((size_t)2 * 1024 * DD * 2);
  unsigned short* wt3 = (unsigned short*)carve((size_t)2 * 512 * DD * 2);
  float* as1 = (float*)carve((size_t)8 * DD * 4);
  float* as2 = (float*)carve((size_t)8 * DD * 4);
  float* as3 = (float*)carve((size_t)4 * DD * 4);
  int* counts = (int*)carve((size_t)NN * 4);
  int* offs = (int*)carve(((size_t)NN + 1) * 4);
  int* cursor = (int*)carve((size_t)NN * 4);
  int* srcs = (int*)carve((size_t)ET * 4);
  size_t needed = (size_t)(p - (char*)d_ws);
  if (needed > ws_size) return;

  k_wtr<<<160, 256, 0, stream>>>(W1l, W1r, W2l, W2r, W3l, W3r, wt1, wt2, wt3, counts);
  k_prep<<<6847, 256, 0, stream>>>(x, ei, att1, att2, att3, as1, as2, as3, abf, counts);
  k_scan<<<1, 1024, 0, stream>>>(counts, offs, cursor);
  k_fill<<<(ET + 255) / 256, 256, 0, stream>>>(ei, cursor, srcs);

  const int gx = (NN + 63) / 64;     // 782
  const int ga = (NN + 1) / 2;       // 25000 blocks (2 nodes each)
  // layer 1: resid = x (f32), write h -> abf (bf16 only)
  gemm64<<<gx * 32, 256, 0, stream>>>(abf, wt1, xl, xr, NN, 1024, 5);
  gat_agg8<8><<<ga, 256, 0, stream>>>(xl, xr, offs, srcs, as1, b1, x, nullptr,
                                      nullptr, abf, 1);
  // layer 2: resid = abf (bf16), write h -> abf in place
  gemm64<<<gx * 32, 256, 0, stream>>>(abf, wt2, xl, xr, NN, 1024, 5);
  gat_agg8<8><<<ga, 256, 0, stream>>>(xl, xr, offs, srcs, as2, b2, nullptr, abf,
                                      nullptr, abf, 1);
  // layer 3: resid = abf (bf16), write final f32 out
  gemm64<<<gx * 16, 256, 0, stream>>>(abf, wt3, xl, xr, NN, 512, 4);
  gat_agg8<4><<<ga, 256, 0, stream>>>(xl, xr, offs, srcs, as3, b3, nullptr, abf,
                                      out, nullptr, 0);
}